// Round 1
// baseline (3218.402 us; speedup 1.0000x reference)
//
#include <hip/hip_runtime.h>
#include <stdint.h>

// ---------------------------------------------------------------------------
// ConditionalDecoder: emb-gather -> LSTM x2 -> FiLM -> vocab GEMM
// B=16, T=256 (L1-1), V=32000, E=H=Z=256, 4H=1024
// Round 0: correctness-first baseline.
//   - all weight matmuls in bf16 MFMA (16x16x32), fp32 accum
//   - recurrence h,c in fp32; 512 per-step kernel launches (no cross-WG sync)
// ---------------------------------------------------------------------------

#define B_  16
#define T_  256
#define H_  256
#define V_  32000
#define G4  1024

typedef unsigned short u16;
typedef __attribute__((ext_vector_type(8))) short  short8;
typedef __attribute__((ext_vector_type(4))) short  short4v;
typedef __attribute__((ext_vector_type(4))) float  f32x4;

static __device__ __forceinline__ float bf2f(u16 u) {
  uint32_t i = ((uint32_t)u) << 16;
  return __builtin_bit_cast(float, i);
}
static __device__ __forceinline__ u16 f2bf(float f) {
  uint32_t i = __builtin_bit_cast(uint32_t, f);
  uint32_t lsb = (i >> 16) & 1u;
  i += 0x7fffu + lsb;
  return (u16)(i >> 16);
}
static __device__ __forceinline__ float sigf(float x) {
  return 1.0f / (1.0f + __expf(-x));
}
static __device__ __forceinline__ float tanhfast(float x) {
  // exact algebraic form (e^2x-1)/(e^2x+1); __expf error ~1e-6 rel
  return 1.0f - 2.0f / (1.0f + __expf(2.0f * x));
}

// ------------------------------ prep kernels -------------------------------

__global__ void k_convert(const float* __restrict__ src, u16* __restrict__ dst, int n) {
  int i = blockIdx.x * blockDim.x + threadIdx.x;
  int stride = gridDim.x * blockDim.x;
  for (; i < n; i += stride) dst[i] = f2bf(src[i]);
}

__global__ void k_addbias(const float* __restrict__ a, const float* __restrict__ b,
                          float* __restrict__ dst, int n) {
  int i = blockIdx.x * blockDim.x + threadIdx.x;
  if (i < n) dst[i] = a[i] + b[i];
}

// gamma = z@Wg.T + bg ; beta = z@Wb.T + bb   (each (16,256))
__global__ void k_film(const float* __restrict__ z,
                       const float* __restrict__ Wg, const float* __restrict__ bg,
                       const float* __restrict__ Wb, const float* __restrict__ bb,
                       float* __restrict__ gamma, float* __restrict__ beta) {
  int tid = blockIdx.x * blockDim.x + threadIdx.x;   // 8192
  int which = tid >> 12;
  int o = tid & 4095;
  int b = o >> 8, h = o & 255;
  const float* W  = which ? Wb : Wg;
  const float* bi = which ? bb : bg;
  float acc = bi[h];
  const float* zr = z + b * 256;
  const float* wr = W + h * 256;
  #pragma unroll 8
  for (int k = 0; k < 256; k++) acc += zr[k] * wr[k];
  (which ? beta : gamma)[o] = acc;
}

// x[b][t][:] = (seq[b][t]==0 ? 0 : emb[seq[b][t]])  as bf16, t in [0,256)
__global__ void k_gather(const int* __restrict__ seq, const float* __restrict__ emb,
                         u16* __restrict__ xb) {
  int i = blockIdx.x * blockDim.x + threadIdx.x;     // B*T*(E/4) = 262144
  int n = B_ * T_ * (H_ / 4);
  if (i >= n) return;
  int e4 = i & 63;
  int bt = i >> 6;
  int t = bt & 255, b = bt >> 8;
  int row = seq[b * 257 + t];
  short4v p;
  if (row == 0) {
    p[0] = 0; p[1] = 0; p[2] = 0; p[3] = 0;
  } else {
    const f32x4 v = *(const f32x4*)(emb + (size_t)row * 256 + e4 * 4);
    p[0] = (short)f2bf(v[0]); p[1] = (short)f2bf(v[1]);
    p[2] = (short)f2bf(v[2]); p[3] = (short)f2bf(v[3]);
  }
  *(short4v*)(xb + (size_t)bt * 256 + e4 * 4) = p;
}

// ------------------------------ bf16 GEMM ----------------------------------
// C(M,N) fp32 = A(M,K)bf16 @ B(N,K)bf16^T + bias(N).  M,N mult of 128, K mult of 32.

#define GBM 128
#define GBN 128
#define GLD 40   // padded LDS row stride (bf16 elems): 80B rows -> ~2-way conflicts

__global__ __launch_bounds__(256) void k_gemm_bt(
    const u16* __restrict__ A, const u16* __restrict__ Bm,
    const float* __restrict__ bias, float* __restrict__ C,
    int M, int N, int K) {
  __shared__ u16 sA[GBM * GLD];
  __shared__ u16 sB[GBN * GLD];
  const int tid  = threadIdx.x;
  const int lane = tid & 63;
  const int wv   = tid >> 6;
  const int wr   = wv >> 1, wc = wv & 1;
  const int m0 = blockIdx.y * GBM, n0 = blockIdx.x * GBN;
  const int rr = tid >> 2;           // 0..63
  const int cc = (tid & 3) * 8;      // 0,8,16,24

  f32x4 acc[4][4];
  #pragma unroll
  for (int m = 0; m < 4; m++)
    #pragma unroll
    for (int n = 0; n < 4; n++) acc[m][n] = (f32x4){0.f, 0.f, 0.f, 0.f};

  for (int ks = 0; ks < K; ks += 32) {
    short8 va0 = *(const short8*)(A  + (size_t)(m0 + rr)      * K + ks + cc);
    short8 va1 = *(const short8*)(A  + (size_t)(m0 + rr + 64) * K + ks + cc);
    short8 vb0 = *(const short8*)(Bm + (size_t)(n0 + rr)      * K + ks + cc);
    short8 vb1 = *(const short8*)(Bm + (size_t)(n0 + rr + 64) * K + ks + cc);
    __syncthreads();
    *(short8*)&sA[(rr)      * GLD + cc] = va0;
    *(short8*)&sA[(rr + 64) * GLD + cc] = va1;
    *(short8*)&sB[(rr)      * GLD + cc] = vb0;
    *(short8*)&sB[(rr + 64) * GLD + cc] = vb1;
    __syncthreads();
    const int kc = (lane >> 4) * 8;
    short8 af[4], bfr[4];
    #pragma unroll
    for (int m = 0; m < 4; m++)
      af[m] = *(const short8*)&sA[(wr * 64 + m * 16 + (lane & 15)) * GLD + kc];
    #pragma unroll
    for (int n = 0; n < 4; n++)
      bfr[n] = *(const short8*)&sB[(wc * 64 + n * 16 + (lane & 15)) * GLD + kc];
    #pragma unroll
    for (int m = 0; m < 4; m++)
      #pragma unroll
      for (int n = 0; n < 4; n++)
        acc[m][n] = __builtin_amdgcn_mfma_f32_16x16x32_bf16(af[m], bfr[n], acc[m][n], 0, 0, 0);
  }

  #pragma unroll
  for (int m = 0; m < 4; m++) {
    int row = m0 + wr * 64 + m * 16 + ((lane >> 4) << 2);
    #pragma unroll
    for (int n = 0; n < 4; n++) {
      int col = n0 + wc * 64 + n * 16 + (lane & 15);
      float bv = bias[col];
      #pragma unroll
      for (int i = 0; i < 4; i++)
        C[(size_t)(row + i) * N + col] = acc[m][n][i] + bv;
    }
  }
}

// ------------------------------ LSTM step ----------------------------------
// One time step. Grid: 64 blocks x 256 thr. Block g owns h-slice [g*4, g*4+4).
// gates(s,j) = Xpre[s,t,j] + sum_k h(s,k) * Whh[j,k]   (Whh bf16, h fp32)
// mode 0: outb = bf16(h_new) into h1 (B,T,H)
// mode 1: outb = bf16(gamma*h_new + beta) into filmed (B,T,H)

#define SWLD 280   // bf16 elems per sW row (560B: 16B-aligned, spreads banks)
#define SHLD 260   // f32 elems per sH row (1040B)

__global__ __launch_bounds__(256) void k_lstm_step(
    const float* __restrict__ Xpre, const u16* __restrict__ Whh,
    const float* __restrict__ h_in, float* __restrict__ h_out,
    float* __restrict__ c, u16* __restrict__ outb,
    const float* __restrict__ gamma, const float* __restrict__ beta,
    int t, int mode) {
  __shared__ u16   sW[16][SWLD];
  __shared__ float sH[16][SHLD];
  __shared__ float sG[16][16];
  const int g = blockIdx.x;
  const int tid = threadIdx.x;

  // stage h(t-1): 16x256 fp32
  if (t == 0) {
    #pragma unroll
    for (int it = 0; it < 4; it++) {
      int c4 = tid + it * 256;
      int s = c4 >> 6, k4 = c4 & 63;
      *(f32x4*)&sH[s][k4 * 4] = (f32x4){0.f, 0.f, 0.f, 0.f};
    }
  } else {
    #pragma unroll
    for (int it = 0; it < 4; it++) {
      int c4 = tid + it * 256;
      int s = c4 >> 6, k4 = c4 & 63;
      *(f32x4*)&sH[s][k4 * 4] = *(const f32x4*)(h_in + s * 256 + k4 * 4);
    }
  }
  // stage Whh slice: 16 rows (4 per gate type) x 256 bf16
  #pragma unroll
  for (int it = 0; it < 2; it++) {
    int ch = tid + it * 256;           // 0..511
    int r = ch >> 5, c8 = ch & 31;
    int gt = r >> 2, hh = r & 3;
    int grow = gt * 256 + g * 4 + hh;
    *(short8*)&sW[r][c8 * 8] = *(const short8*)(Whh + (size_t)grow * 256 + c8 * 8);
  }
  __syncthreads();

  // one 256-deep dot per thread: (sample s, local gate row r)
  {
    const int s = tid >> 4, r = tid & 15;
    const int gt = r >> 2, hh = r & 3;
    const int grow = gt * 256 + g * 4 + hh;
    float acc = Xpre[((size_t)(s * 256 + t)) * 1024 + grow];
    #pragma unroll 4
    for (int k = 0; k < 256; k += 8) {
      short8 w8 = *(const short8*)&sW[r][k];
      f32x4 ha = *(const f32x4*)&sH[s][k];
      f32x4 hb = *(const f32x4*)&sH[s][k + 4];
      acc += bf2f((u16)w8[0]) * ha[0];
      acc += bf2f((u16)w8[1]) * ha[1];
      acc += bf2f((u16)w8[2]) * ha[2];
      acc += bf2f((u16)w8[3]) * ha[3];
      acc += bf2f((u16)w8[4]) * hb[0];
      acc += bf2f((u16)w8[5]) * hb[1];
      acc += bf2f((u16)w8[6]) * hb[2];
      acc += bf2f((u16)w8[7]) * hb[3];
    }
    sG[s][r] = acc;
  }
  __syncthreads();

  if (tid < 64) {
    int ss = tid >> 2, h4 = tid & 3;
    float iv = sG[ss][0 + h4];
    float fv = sG[ss][4 + h4];
    float gv = sG[ss][8 + h4];
    float ov = sG[ss][12 + h4];
    int idx = ss * 256 + g * 4 + h4;
    float cold = (t == 0) ? 0.f : c[idx];
    float cn = sigf(fv) * cold + sigf(iv) * tanhfast(gv);
    float hn = sigf(ov) * tanhfast(cn);
    c[idx] = cn;
    h_out[idx] = hn;
    size_t oofs = ((size_t)(ss * 256 + t)) * 256 + g * 4 + h4;
    if (mode == 0) {
      outb[oofs] = f2bf(hn);
    } else {
      outb[oofs] = f2bf(gamma[idx] * hn + beta[idx]);
    }
  }
}

// ------------------------------ launcher -----------------------------------

extern "C" void kernel_launch(void* const* d_in, const int* in_sizes, int n_in,
                              void* d_out, int out_size, void* d_ws, size_t ws_size,
                              hipStream_t stream) {
  const float* z    = (const float*)d_in[0];
  const int*   seq  = (const int*)  d_in[1];
  const float* emb  = (const float*)d_in[2];
  const float* Wg   = (const float*)d_in[3];
  const float* bg   = (const float*)d_in[4];
  const float* Wb   = (const float*)d_in[5];
  const float* bb   = (const float*)d_in[6];
  const float* Wih0 = (const float*)d_in[7];
  const float* Whh0 = (const float*)d_in[8];
  const float* bih0 = (const float*)d_in[9];
  const float* bhh0 = (const float*)d_in[10];
  const float* Wih1 = (const float*)d_in[11];
  const float* Whh1 = (const float*)d_in[12];
  const float* bih1 = (const float*)d_in[13];
  const float* bhh1 = (const float*)d_in[14];
  const float* Wout = (const float*)d_in[15];
  const float* bout = (const float*)d_in[16];

  char* ws = (char*)d_ws;
  size_t off = 0;
  auto take = [&](size_t bytes) -> char* {
    char* p = ws + off;
    off = (off + bytes + 255) & ~(size_t)255;
    return p;
  };
  float* gamma  = (float*)take(B_ * H_ * 4);
  float* beta   = (float*)take(B_ * H_ * 4);
  float* b01    = (float*)take(G4 * 4);
  float* b11    = (float*)take(G4 * 4);
  u16*   Wih0b  = (u16*)  take((size_t)G4 * H_ * 2);
  u16*   Whh0b  = (u16*)  take((size_t)G4 * H_ * 2);
  u16*   Wih1b  = (u16*)  take((size_t)G4 * H_ * 2);
  u16*   Whh1b  = (u16*)  take((size_t)G4 * H_ * 2);
  u16*   Woutb  = (u16*)  take((size_t)V_ * H_ * 2);
  u16*   xb     = (u16*)  take((size_t)B_ * T_ * H_ * 2);
  float* X      = (float*)take((size_t)B_ * T_ * G4 * 4);
  u16*   h1b    = (u16*)  take((size_t)B_ * T_ * H_ * 2);
  u16*   filmb  = (u16*)  take((size_t)B_ * T_ * H_ * 2);
  float* hA     = (float*)take(B_ * H_ * 4);
  float* hB     = (float*)take(B_ * H_ * 4);
  float* cbuf   = (float*)take(B_ * H_ * 4);
  (void)ws_size; (void)in_sizes; (void)n_in; (void)out_size;

  // prep
  k_convert<<<256, 256, 0, stream>>>(Wih0, Wih0b, G4 * H_);
  k_convert<<<256, 256, 0, stream>>>(Whh0, Whh0b, G4 * H_);
  k_convert<<<256, 256, 0, stream>>>(Wih1, Wih1b, G4 * H_);
  k_convert<<<256, 256, 0, stream>>>(Whh1, Whh1b, G4 * H_);
  k_convert<<<1024, 256, 0, stream>>>(Wout, Woutb, V_ * H_);
  k_addbias<<<4, 256, 0, stream>>>(bih0, bhh0, b01, G4);
  k_addbias<<<4, 256, 0, stream>>>(bih1, bhh1, b11, G4);
  k_film<<<32, 256, 0, stream>>>(z, Wg, bg, Wb, bb, gamma, beta);
  k_gather<<<1024, 256, 0, stream>>>(seq, emb, xb);

  // layer 0 input projection: X0 = x @ Wih0^T + (bih0+bhh0)
  k_gemm_bt<<<dim3(G4 / GBN, (B_ * T_) / GBM), 256, 0, stream>>>(
      xb, Wih0b, b01, X, B_ * T_, G4, H_);

  for (int t = 0; t < T_; t++) {
    const float* hi = (t & 1) ? hB : hA;
    float*       ho = (t & 1) ? hA : hB;
    k_lstm_step<<<64, 256, 0, stream>>>(X, Whh0b, hi, ho, cbuf, h1b,
                                        gamma, beta, t, 0);
  }

  // layer 1 input projection: X1 = h1 @ Wih1^T + (bih1+bhh1)
  k_gemm_bt<<<dim3(G4 / GBN, (B_ * T_) / GBM), 256, 0, stream>>>(
      h1b, Wih1b, b11, X, B_ * T_, G4, H_);

  for (int t = 0; t < T_; t++) {
    const float* hi = (t & 1) ? hB : hA;
    float*       ho = (t & 1) ? hA : hB;
    k_lstm_step<<<64, 256, 0, stream>>>(X, Whh1b, hi, ho, cbuf, filmb,
                                        gamma, beta, t, 1);
  }

  // logits = filmed @ Wout^T + b_out
  k_gemm_bt<<<dim3(V_ / GBN, (B_ * T_) / GBM), 256, 0, stream>>>(
      filmb, Woutb, bout, (float*)d_out, B_ * T_, V_, H_);
}

// Round 3
// 1616.224 us; speedup vs baseline: 1.9913x; 1.9913x over previous
//
#include <hip/hip_runtime.h>
#include <stdint.h>

// ---------------------------------------------------------------------------
// ConditionalDecoder: emb-gather -> LSTM x2 -> FiLM -> vocab GEMM
// B=16, T=256, V=32000, E=H=Z=256, 4H=1024
// Round 2: same as round 1 (persistent LSTM, 16-block flag sync); fence
//          builtin fixed for this ROCm (__builtin_amdgcn_fence).
// ---------------------------------------------------------------------------

#define B_  16
#define T_  256
#define H_  256
#define V_  32000
#define G4  1024
#define NBLK 16
#define FSTR 32   // flag stride (ints) -> one cacheline per flag

typedef unsigned short u16;
typedef __attribute__((ext_vector_type(8))) short  short8;
typedef __attribute__((ext_vector_type(4))) short  short4v;
typedef __attribute__((ext_vector_type(4))) float  f32x4;

static __device__ __forceinline__ float bf2f(u16 u) {
  uint32_t i = ((uint32_t)u) << 16;
  return __builtin_bit_cast(float, i);
}
static __device__ __forceinline__ u16 f2bf(float f) {
  uint32_t i = __builtin_bit_cast(uint32_t, f);
  uint32_t lsb = (i >> 16) & 1u;
  i += 0x7fffu + lsb;
  return (u16)(i >> 16);
}
static __device__ __forceinline__ float sigf(float x) {
  return 1.0f / (1.0f + __expf(-x));
}
static __device__ __forceinline__ float tanhfast(float x) {
  return 1.0f - 2.0f / (1.0f + __expf(2.0f * x));
}

// ------------------------------ prep kernels -------------------------------

__global__ void k_convert(const float* __restrict__ src, u16* __restrict__ dst, int n) {
  int i = blockIdx.x * blockDim.x + threadIdx.x;
  int stride = gridDim.x * blockDim.x;
  for (; i < n; i += stride) dst[i] = f2bf(src[i]);
}

__global__ void k_addbias(const float* __restrict__ a, const float* __restrict__ b,
                          float* __restrict__ dst, int n) {
  int i = blockIdx.x * blockDim.x + threadIdx.x;
  if (i < n) dst[i] = a[i] + b[i];
}

__global__ void k_zeroi(int* __restrict__ p, int n) {
  int i = blockIdx.x * blockDim.x + threadIdx.x;
  if (i < n) p[i] = 0;
}

// gamma = z@Wg.T + bg ; beta = z@Wb.T + bb   (each (16,256))
__global__ void k_film(const float* __restrict__ z,
                       const float* __restrict__ Wg, const float* __restrict__ bg,
                       const float* __restrict__ Wb, const float* __restrict__ bb,
                       float* __restrict__ gamma, float* __restrict__ beta) {
  int tid = blockIdx.x * blockDim.x + threadIdx.x;   // 8192
  int which = tid >> 12;
  int o = tid & 4095;
  int b = o >> 8, h = o & 255;
  const float* W  = which ? Wb : Wg;
  const float* bi = which ? bb : bg;
  float acc = bi[h];
  const float* zr = z + b * 256;
  const float* wr = W + h * 256;
  #pragma unroll 8
  for (int k = 0; k < 256; k++) acc += zr[k] * wr[k];
  (which ? beta : gamma)[o] = acc;
}

// x[b][t][:] = (seq[b][t]==0 ? 0 : emb[seq[b][t]])  as bf16
__global__ void k_gather(const int* __restrict__ seq, const float* __restrict__ emb,
                         u16* __restrict__ xb) {
  int i = blockIdx.x * blockDim.x + threadIdx.x;     // B*T*(E/4) = 262144
  int n = B_ * T_ * (H_ / 4);
  if (i >= n) return;
  int e4 = i & 63;
  int bt = i >> 6;
  int t = bt & 255, b = bt >> 8;
  int row = seq[b * 257 + t];
  short4v p;
  if (row == 0) {
    p[0] = 0; p[1] = 0; p[2] = 0; p[3] = 0;
  } else {
    const f32x4 v = *(const f32x4*)(emb + (size_t)row * 256 + e4 * 4);
    p[0] = (short)f2bf(v[0]); p[1] = (short)f2bf(v[1]);
    p[2] = (short)f2bf(v[2]); p[3] = (short)f2bf(v[3]);
  }
  *(short4v*)(xb + (size_t)bt * 256 + e4 * 4) = p;
}

// ------------------------------ bf16 GEMM ----------------------------------
// C(M,N) fp32 = A(M,K)bf16 @ B(N,K)bf16^T + bias(N). M,N mult of 128, K mult of 32.

#define GBM 128
#define GBN 128
#define GLD 40

__global__ __launch_bounds__(256) void k_gemm_bt(
    const u16* __restrict__ A, const u16* __restrict__ Bm,
    const float* __restrict__ bias, float* __restrict__ C,
    int M, int N, int K) {
  __shared__ u16 sA[GBM * GLD];
  __shared__ u16 sB[GBN * GLD];
  const int tid  = threadIdx.x;
  const int lane = tid & 63;
  const int wv   = tid >> 6;
  const int wr   = wv >> 1, wc = wv & 1;
  const int m0 = blockIdx.y * GBM, n0 = blockIdx.x * GBN;
  const int rr = tid >> 2;
  const int cc = (tid & 3) * 8;

  f32x4 acc[4][4];
  #pragma unroll
  for (int m = 0; m < 4; m++)
    #pragma unroll
    for (int n = 0; n < 4; n++) acc[m][n] = (f32x4){0.f, 0.f, 0.f, 0.f};

  for (int ks = 0; ks < K; ks += 32) {
    short8 va0 = *(const short8*)(A  + (size_t)(m0 + rr)      * K + ks + cc);
    short8 va1 = *(const short8*)(A  + (size_t)(m0 + rr + 64) * K + ks + cc);
    short8 vb0 = *(const short8*)(Bm + (size_t)(n0 + rr)      * K + ks + cc);
    short8 vb1 = *(const short8*)(Bm + (size_t)(n0 + rr + 64) * K + ks + cc);
    __syncthreads();
    *(short8*)&sA[(rr)      * GLD + cc] = va0;
    *(short8*)&sA[(rr + 64) * GLD + cc] = va1;
    *(short8*)&sB[(rr)      * GLD + cc] = vb0;
    *(short8*)&sB[(rr + 64) * GLD + cc] = vb1;
    __syncthreads();
    const int kc = (lane >> 4) * 8;
    short8 af[4], bfr[4];
    #pragma unroll
    for (int m = 0; m < 4; m++)
      af[m] = *(const short8*)&sA[(wr * 64 + m * 16 + (lane & 15)) * GLD + kc];
    #pragma unroll
    for (int n = 0; n < 4; n++)
      bfr[n] = *(const short8*)&sB[(wc * 64 + n * 16 + (lane & 15)) * GLD + kc];
    #pragma unroll
    for (int m = 0; m < 4; m++)
      #pragma unroll
      for (int n = 0; n < 4; n++)
        acc[m][n] = __builtin_amdgcn_mfma_f32_16x16x32_bf16(af[m], bfr[n], acc[m][n], 0, 0, 0);
  }

  #pragma unroll
  for (int m = 0; m < 4; m++) {
    int row = m0 + wr * 64 + m * 16 + ((lane >> 4) << 2);
    #pragma unroll
    for (int n = 0; n < 4; n++) {
      int col = n0 + wc * 64 + n * 16 + (lane & 15);
      float bv = bias[col];
      #pragma unroll
      for (int i = 0; i < 4; i++)
        C[(size_t)(row + i) * N + col] = acc[m][n][i] + bv;
    }
  }
}

// ------------------------- persistent LSTM layer ---------------------------
// 16 blocks x 256 threads. Block g owns h-cols [g*16, g*16+16).
// Wave w (0..3) computes gate w for those cols via MFMA; W_hh frags live in
// registers for all 256 steps. h exchanged as bf16 through global memory with
// per-block flags (device scope). c-state stays in registers.
// mode 0: outb = bf16(h);  mode 1: outb = bf16(gamma*h + beta).

__global__ __launch_bounds__(256) void k_lstm_seq(
    const float* __restrict__ Xpre,    // (B,T,1024) fp32, row = s*T + t
    const u16* __restrict__ Whh,       // (1024,256) bf16
    u16* __restrict__ hb,              // 2*B*H bf16 rolling h buffers
    int* __restrict__ flags,           // NBLK*FSTR ints, pre-zeroed
    u16* __restrict__ outb,            // (B,T,H) bf16
    const float* __restrict__ gamma, const float* __restrict__ beta,
    int mode) {
  __shared__ u16   sH[16][264];
  __shared__ float sG[16][68];
  const int g = blockIdx.x;
  const int tid = threadIdx.x;
  const int lane = tid & 63;
  const int w = tid >> 6;                 // wave index == gate index

  // B-fragments of W_hh, resident across all steps.
  short8 wf[8];
  {
    const int grow = w * 256 + g * 16 + (lane & 15);
    const int kb = (lane >> 4) * 8;
    #pragma unroll
    for (int ks = 0; ks < 8; ks++)
      wf[ks] = *(const short8*)(Whh + (size_t)grow * 256 + ks * 32 + kb);
  }

  const int s_ = tid >> 4, c_ = tid & 15;  // nonlinearity mapping
  const int hcol = g * 16 + c_;
  float cstate = 0.f;
  float gmv = 1.f, btv = 0.f;
  if (mode) { gmv = gamma[s_ * 256 + hcol]; btv = beta[s_ * 256 + hcol]; }

  for (int t = 0; t < T_; t++) {
    // Xpre loads issued early; they complete under the spin.
    const size_t xbase = ((size_t)(s_ * T_ + t)) * 1024 + (size_t)g * 16 + c_;
    float gi = Xpre[xbase];
    float gf = Xpre[xbase + 256];
    float gg = Xpre[xbase + 512];
    float go = Xpre[xbase + 768];

    if (t > 0) {
      if (tid < NBLK) {
        while (__hip_atomic_load(&flags[tid * FSTR], __ATOMIC_RELAXED,
                                 __HIP_MEMORY_SCOPE_AGENT) < t) { }
      }
      __syncthreads();
      __builtin_amdgcn_fence(__ATOMIC_ACQUIRE, "agent");

      // stage h(t-1) (bf16, 8KB) to LDS, coalesced
      const u16* hsrc = hb + ((t + 1) & 1) * (B_ * H_);
      {
        const int ss = tid >> 4, k0 = (tid & 15) * 16;
        short8 v0 = *(const short8*)(hsrc + ss * 256 + k0);
        short8 v1 = *(const short8*)(hsrc + ss * 256 + k0 + 8);
        *(short8*)&sH[ss][k0] = v0;
        *(short8*)&sH[ss][k0 + 8] = v1;
      }
      __syncthreads();

      // h @ Whh^T for this block's 64 gate cols (wave w -> gate w)
      const int ar = lane & 15;
      const int kb = (lane >> 4) * 8;
      f32x4 acc0 = {0.f, 0.f, 0.f, 0.f}, acc1 = {0.f, 0.f, 0.f, 0.f};
      #pragma unroll
      for (int ks = 0; ks < 4; ks++) {
        short8 a0 = *(const short8*)&sH[ar][ks * 32 + kb];
        short8 a1 = *(const short8*)&sH[ar][(ks + 4) * 32 + kb];
        acc0 = __builtin_amdgcn_mfma_f32_16x16x32_bf16(a0, wf[ks],     acc0, 0, 0, 0);
        acc1 = __builtin_amdgcn_mfma_f32_16x16x32_bf16(a1, wf[ks + 4], acc1, 0, 0, 0);
      }
      #pragma unroll
      for (int r = 0; r < 4; r++)
        sG[(lane >> 4) * 4 + r][w * 16 + (lane & 15)] = acc0[r] + acc1[r];
      __syncthreads();

      gi += sG[s_][c_];
      gf += sG[s_][16 + c_];
      gg += sG[s_][32 + c_];
      go += sG[s_][48 + c_];
    }

    float cn = sigf(gf) * cstate + sigf(gi) * tanhfast(gg);
    float hn = sigf(go) * tanhfast(cn);
    cstate = cn;
    u16 hnb = f2bf(hn);
    hb[(t & 1) * (B_ * H_) + s_ * 256 + hcol] = hnb;
    outb[((size_t)(s_ * T_ + t)) * 256 + hcol] =
        mode ? f2bf(gmv * hn + btv) : hnb;

    __syncthreads();   // all waves' stores issued before signaling
    if (tid == 0) {
      __builtin_amdgcn_fence(__ATOMIC_RELEASE, "agent");
      __hip_atomic_store(&flags[g * FSTR], t + 1, __ATOMIC_RELAXED,
                         __HIP_MEMORY_SCOPE_AGENT);
    }
  }
}

// ------------------------------ launcher -----------------------------------

extern "C" void kernel_launch(void* const* d_in, const int* in_sizes, int n_in,
                              void* d_out, int out_size, void* d_ws, size_t ws_size,
                              hipStream_t stream) {
  const float* z    = (const float*)d_in[0];
  const int*   seq  = (const int*)  d_in[1];
  const float* emb  = (const float*)d_in[2];
  const float* Wg   = (const float*)d_in[3];
  const float* bg   = (const float*)d_in[4];
  const float* Wb   = (const float*)d_in[5];
  const float* bb   = (const float*)d_in[6];
  const float* Wih0 = (const float*)d_in[7];
  const float* Whh0 = (const float*)d_in[8];
  const float* bih0 = (const float*)d_in[9];
  const float* bhh0 = (const float*)d_in[10];
  const float* Wih1 = (const float*)d_in[11];
  const float* Whh1 = (const float*)d_in[12];
  const float* bih1 = (const float*)d_in[13];
  const float* bhh1 = (const float*)d_in[14];
  const float* Wout = (const float*)d_in[15];
  const float* bout = (const float*)d_in[16];

  char* ws = (char*)d_ws;
  size_t off = 0;
  auto take = [&](size_t bytes) -> char* {
    char* p = ws + off;
    off = (off + bytes + 255) & ~(size_t)255;
    return p;
  };
  float* gamma  = (float*)take(B_ * H_ * 4);
  float* beta   = (float*)take(B_ * H_ * 4);
  float* b01    = (float*)take(G4 * 4);
  float* b11    = (float*)take(G4 * 4);
  u16*   Wih0b  = (u16*)  take((size_t)G4 * H_ * 2);
  u16*   Whh0b  = (u16*)  take((size_t)G4 * H_ * 2);
  u16*   Wih1b  = (u16*)  take((size_t)G4 * H_ * 2);
  u16*   Whh1b  = (u16*)  take((size_t)G4 * H_ * 2);
  u16*   Woutb  = (u16*)  take((size_t)V_ * H_ * 2);
  u16*   xb     = (u16*)  take((size_t)B_ * T_ * H_ * 2);
  float* X      = (float*)take((size_t)B_ * T_ * G4 * 4);
  u16*   h1b    = (u16*)  take((size_t)B_ * T_ * H_ * 2);
  u16*   filmb  = (u16*)  take((size_t)B_ * T_ * H_ * 2);
  u16*   hb     = (u16*)  take(2 * B_ * H_ * 2);
  int*   flags0 = (int*)  take(NBLK * FSTR * 4);
  int*   flags1 = (int*)  take(NBLK * FSTR * 4);
  (void)ws_size; (void)in_sizes; (void)n_in; (void)out_size;

  // prep
  k_convert<<<256, 256, 0, stream>>>(Wih0, Wih0b, G4 * H_);
  k_convert<<<256, 256, 0, stream>>>(Whh0, Whh0b, G4 * H_);
  k_convert<<<256, 256, 0, stream>>>(Wih1, Wih1b, G4 * H_);
  k_convert<<<256, 256, 0, stream>>>(Whh1, Whh1b, G4 * H_);
  k_convert<<<1024, 256, 0, stream>>>(Wout, Woutb, V_ * H_);
  k_addbias<<<4, 256, 0, stream>>>(bih0, bhh0, b01, G4);
  k_addbias<<<4, 256, 0, stream>>>(bih1, bhh1, b11, G4);
  k_zeroi<<<4, 256, 0, stream>>>(flags0, 2 * NBLK * FSTR);  // flags0+flags1
  k_film<<<32, 256, 0, stream>>>(z, Wg, bg, Wb, bb, gamma, beta);
  k_gather<<<1024, 256, 0, stream>>>(seq, emb, xb);

  // layer 0 input projection: X0 = x @ Wih0^T + (bih0+bhh0)
  k_gemm_bt<<<dim3(G4 / GBN, (B_ * T_) / GBM), 256, 0, stream>>>(
      xb, Wih0b, b01, X, B_ * T_, G4, H_);

  // layer 0 recurrence (persistent)
  k_lstm_seq<<<NBLK, 256, 0, stream>>>(X, Whh0b, hb, flags0, h1b,
                                       gamma, beta, 0);

  // layer 1 input projection: X1 = h1 @ Wih1^T + (bih1+bhh1)
  k_gemm_bt<<<dim3(G4 / GBN, (B_ * T_) / GBM), 256, 0, stream>>>(
      h1b, Wih1b, b11, X, B_ * T_, G4, H_);

  // layer 1 recurrence (persistent, FiLM fused into output)
  k_lstm_seq<<<NBLK, 256, 0, stream>>>(X, Whh1b, hb, flags1, filmb,
                                       gamma, beta, 1);

  // logits = filmed @ Wout^T + b_out
  k_gemm_bt<<<dim3(V_ / GBN, (B_ * T_) / GBM), 256, 0, stream>>>(
      filmb, Woutb, bout, (float*)d_out, B_ * T_, V_, H_);
}

// Round 4
// 1203.383 us; speedup vs baseline: 2.6745x; 1.3431x over previous
//
#include <hip/hip_runtime.h>
#include <stdint.h>

// ---------------------------------------------------------------------------
// ConditionalDecoder: emb-gather -> LSTM x2 -> FiLM -> vocab GEMM
// B=16, T=256, V=32000, E=H=Z=256, 4H=1024
// Round 3: per-SAMPLE persistent LSTM blocks (batch dim is independent!).
//   16 blocks x 512 thr; NO inter-block sync. W_hh hybrid-resident:
//   46/64 B-frags in VGPRs + 18/64 in LDS (144KB). h replicated across
//   MFMA A-rows; c-state in registers; one __syncthreads per step.
// ---------------------------------------------------------------------------

#define B_  16
#define T_  256
#define H_  256
#define V_  32000
#define G4  1024

#define LWAVES 8
#define LTPB   512
#define LRES   46        // B-frags resident in VGPRs per wave
#define LSTR   18        // B-frags streamed from LDS per wave

typedef unsigned short u16;
typedef __attribute__((ext_vector_type(8))) short  short8;
typedef __attribute__((ext_vector_type(4))) short  short4v;
typedef __attribute__((ext_vector_type(4))) float  f32x4;

static __device__ __forceinline__ float bf2f(u16 u) {
  uint32_t i = ((uint32_t)u) << 16;
  return __builtin_bit_cast(float, i);
}
static __device__ __forceinline__ u16 f2bf(float f) {
  uint32_t i = __builtin_bit_cast(uint32_t, f);
  uint32_t lsb = (i >> 16) & 1u;
  i += 0x7fffu + lsb;
  return (u16)(i >> 16);
}
static __device__ __forceinline__ float sigf(float x) {
  return 1.0f / (1.0f + __expf(-x));
}
static __device__ __forceinline__ float tanhfast(float x) {
  return 1.0f - 2.0f / (1.0f + __expf(2.0f * x));
}

// ------------------------------ prep kernels -------------------------------

__global__ void k_convert(const float* __restrict__ src, u16* __restrict__ dst, int n) {
  int i = blockIdx.x * blockDim.x + threadIdx.x;
  int stride = gridDim.x * blockDim.x;
  for (; i < n; i += stride) dst[i] = f2bf(src[i]);
}

__global__ void k_addbias(const float* __restrict__ a, const float* __restrict__ b,
                          float* __restrict__ dst, int n) {
  int i = blockIdx.x * blockDim.x + threadIdx.x;
  if (i < n) dst[i] = a[i] + b[i];
}

// gamma = z@Wg.T + bg ; beta = z@Wb.T + bb   (each (16,256))
__global__ void k_film(const float* __restrict__ z,
                       const float* __restrict__ Wg, const float* __restrict__ bg,
                       const float* __restrict__ Wb, const float* __restrict__ bb,
                       float* __restrict__ gamma, float* __restrict__ beta) {
  int tid = blockIdx.x * blockDim.x + threadIdx.x;   // 8192
  int which = tid >> 12;
  int o = tid & 4095;
  int b = o >> 8, h = o & 255;
  const float* W  = which ? Wb : Wg;
  const float* bi = which ? bb : bg;
  float acc = bi[h];
  const float* zr = z + b * 256;
  const float* wr = W + h * 256;
  #pragma unroll 8
  for (int k = 0; k < 256; k++) acc += zr[k] * wr[k];
  (which ? beta : gamma)[o] = acc;
}

// x[b][t][:] = (seq[b][t]==0 ? 0 : emb[seq[b][t]])  as bf16
__global__ void k_gather(const int* __restrict__ seq, const float* __restrict__ emb,
                         u16* __restrict__ xb) {
  int i = blockIdx.x * blockDim.x + threadIdx.x;     // B*T*(E/4) = 262144
  int n = B_ * T_ * (H_ / 4);
  if (i >= n) return;
  int e4 = i & 63;
  int bt = i >> 6;
  int t = bt & 255, b = bt >> 8;
  int row = seq[b * 257 + t];
  short4v p;
  if (row == 0) {
    p[0] = 0; p[1] = 0; p[2] = 0; p[3] = 0;
  } else {
    const f32x4 v = *(const f32x4*)(emb + (size_t)row * 256 + e4 * 4);
    p[0] = (short)f2bf(v[0]); p[1] = (short)f2bf(v[1]);
    p[2] = (short)f2bf(v[2]); p[3] = (short)f2bf(v[3]);
  }
  *(short4v*)(xb + (size_t)bt * 256 + e4 * 4) = p;
}

// ------------------------------ bf16 GEMM ----------------------------------
// C(M,N) fp32 = A(M,K)bf16 @ B(N,K)bf16^T + bias(N). M,N mult of 128, K mult of 32.

#define GBM 128
#define GBN 128
#define GLD 40

__global__ __launch_bounds__(256) void k_gemm_bt(
    const u16* __restrict__ A, const u16* __restrict__ Bm,
    const float* __restrict__ bias, float* __restrict__ C,
    int M, int N, int K) {
  __shared__ u16 sA[GBM * GLD];
  __shared__ u16 sB[GBN * GLD];
  const int tid  = threadIdx.x;
  const int lane = tid & 63;
  const int wv   = tid >> 6;
  const int wr   = wv >> 1, wc = wv & 1;
  const int m0 = blockIdx.y * GBM, n0 = blockIdx.x * GBN;
  const int rr = tid >> 2;
  const int cc = (tid & 3) * 8;

  f32x4 acc[4][4];
  #pragma unroll
  for (int m = 0; m < 4; m++)
    #pragma unroll
    for (int n = 0; n < 4; n++) acc[m][n] = (f32x4){0.f, 0.f, 0.f, 0.f};

  for (int ks = 0; ks < K; ks += 32) {
    short8 va0 = *(const short8*)(A  + (size_t)(m0 + rr)      * K + ks + cc);
    short8 va1 = *(const short8*)(A  + (size_t)(m0 + rr + 64) * K + ks + cc);
    short8 vb0 = *(const short8*)(Bm + (size_t)(n0 + rr)      * K + ks + cc);
    short8 vb1 = *(const short8*)(Bm + (size_t)(n0 + rr + 64) * K + ks + cc);
    __syncthreads();
    *(short8*)&sA[(rr)      * GLD + cc] = va0;
    *(short8*)&sA[(rr + 64) * GLD + cc] = va1;
    *(short8*)&sB[(rr)      * GLD + cc] = vb0;
    *(short8*)&sB[(rr + 64) * GLD + cc] = vb1;
    __syncthreads();
    const int kc = (lane >> 4) * 8;
    short8 af[4], bfr[4];
    #pragma unroll
    for (int m = 0; m < 4; m++)
      af[m] = *(const short8*)&sA[(wr * 64 + m * 16 + (lane & 15)) * GLD + kc];
    #pragma unroll
    for (int n = 0; n < 4; n++)
      bfr[n] = *(const short8*)&sB[(wc * 64 + n * 16 + (lane & 15)) * GLD + kc];
    #pragma unroll
    for (int m = 0; m < 4; m++)
      #pragma unroll
      for (int n = 0; n < 4; n++)
        acc[m][n] = __builtin_amdgcn_mfma_f32_16x16x32_bf16(af[m], bfr[n], acc[m][n], 0, 0, 0);
  }

  #pragma unroll
  for (int m = 0; m < 4; m++) {
    int row = m0 + wr * 64 + m * 16 + ((lane >> 4) << 2);
    #pragma unroll
    for (int n = 0; n < 4; n++) {
      int col = n0 + wc * 64 + n * 16 + (lane & 15);
      float bv = bias[col];
      #pragma unroll
      for (int i = 0; i < 4; i++)
        C[(size_t)(row + i) * N + col] = acc[m][n][i] + bv;
    }
  }
}

// ------------------------- per-sample LSTM ---------------------------------
// Block = one sample. 8 waves; wave w owns h-cols [w*32, w*32+16) and
// [w*32+16, w*32+32) for all 4 gates = 8 MFMA N-tiles. tile = gate*2 + cb.
// B-frag f = tile*8 + ks: f < LRES in VGPRs, else LDS (staged pre-loop).
// A = h(t-1) bf16 replicated over all 16 MFMA rows (rows identical).
// mode 0: outb = bf16(h);  mode 1: outb = bf16(gamma*h + beta).

#define LDSF(fi) (*(const short8*)&sWf[((w * LSTR + (fi)) * 64 + lane) * 8])

__global__ __launch_bounds__(LTPB) void k_lstm_sample(
    const float* __restrict__ Xpre,    // (B*T, 1024) fp32, row = s*T + t
    const u16* __restrict__ Whh,       // (1024,256) bf16
    u16* __restrict__ outb,            // (B,T,H) bf16
    const float* __restrict__ gamma, const float* __restrict__ beta,
    int mode) {
  __shared__ u16 sWf[LWAVES * LSTR * 64 * 8];   // 144 KB streamed W frags
  __shared__ u16 hbuf[2][288];                  // h double buffer (bf16)

  const int s    = blockIdx.x;
  const int tid  = threadIdx.x;
  const int lane = tid & 63;
  const int w    = tid >> 6;
  const int l15  = lane & 15;
  const int lhi  = lane >> 4;

  // ---- stage W_hh fragments: 46 resident, 18 -> LDS ----
  short8 wreg[LRES];
  #pragma unroll
  for (int tile = 0; tile < 8; ++tile) {
    const int row = (tile >> 1) * 256 + w * 32 + (tile & 1) * 16 + l15;
    const u16* wp = Whh + (size_t)row * 256 + lhi * 8;
    #pragma unroll
    for (int ks = 0; ks < 8; ++ks) {
      short8 v = *(const short8*)(wp + ks * 32);
      const int f = tile * 8 + ks;
      if (f < LRES) wreg[f] = v;
      else *(short8*)&sWf[((w * LSTR + (f - LRES)) * 64 + lane) * 8] = v;
    }
  }

  const int col0 = w * 32 + l15;
  const int col1 = col0 + 16;
  float cs0 = 0.f, cs1 = 0.f;
  float gm0 = 1.f, gm1 = 1.f, bt0 = 0.f, bt1 = 0.f;
  if (mode) {
    gm0 = gamma[s * 256 + col0]; bt0 = beta[s * 256 + col0];
    gm1 = gamma[s * 256 + col1]; bt1 = beta[s * 256 + col1];
  }

  for (int t = 0; t < T_; ++t) {
    // gate pre-activations from Xpre (issued early, consumed after MFMA)
    const size_t xb0 = ((size_t)(s * T_ + t)) * 1024 + (size_t)(w * 32 + l15);
    float xi0 = Xpre[xb0],       xi1 = Xpre[xb0 + 16];
    float xf0 = Xpre[xb0 + 256], xf1 = Xpre[xb0 + 272];
    float xg0 = Xpre[xb0 + 512], xg1 = Xpre[xb0 + 528];
    float xo0 = Xpre[xb0 + 768], xo1 = Xpre[xb0 + 784];

    f32x4 acc[8];
    #pragma unroll
    for (int i = 0; i < 8; ++i) acc[i] = (f32x4){0.f, 0.f, 0.f, 0.f};

    if (t > 0) {
      const u16* hrd = hbuf[(t + 1) & 1];
      #pragma unroll
      for (int ks = 0; ks < 8; ++ks) {
        short8 a = *(const short8*)&hrd[ks * 32 + lhi * 8];
        acc[0] = __builtin_amdgcn_mfma_f32_16x16x32_bf16(a, wreg[ks],      acc[0], 0, 0, 0);
        acc[1] = __builtin_amdgcn_mfma_f32_16x16x32_bf16(a, wreg[8 + ks],  acc[1], 0, 0, 0);
        acc[2] = __builtin_amdgcn_mfma_f32_16x16x32_bf16(a, wreg[16 + ks], acc[2], 0, 0, 0);
        acc[3] = __builtin_amdgcn_mfma_f32_16x16x32_bf16(a, wreg[24 + ks], acc[3], 0, 0, 0);
        acc[4] = __builtin_amdgcn_mfma_f32_16x16x32_bf16(a, wreg[32 + ks], acc[4], 0, 0, 0);
        if (40 + ks < LRES)
          acc[5] = __builtin_amdgcn_mfma_f32_16x16x32_bf16(a, wreg[40 + ks], acc[5], 0, 0, 0);
        else
          acc[5] = __builtin_amdgcn_mfma_f32_16x16x32_bf16(a, LDSF(ks - 6),  acc[5], 0, 0, 0);
        acc[6] = __builtin_amdgcn_mfma_f32_16x16x32_bf16(a, LDSF(2 + ks),  acc[6], 0, 0, 0);
        acc[7] = __builtin_amdgcn_mfma_f32_16x16x32_bf16(a, LDSF(10 + ks), acc[7], 0, 0, 0);
      }
    }

    // nonlinearity (all row-groups hold identical values; lhi==0 writes)
    {
      float iv = acc[0][0] + xi0, fv = acc[2][0] + xf0;
      float gv = acc[4][0] + xg0, ov = acc[6][0] + xo0;
      float cn = sigf(fv) * cs0 + sigf(iv) * tanhfast(gv);
      float hn = sigf(ov) * tanhfast(cn);
      cs0 = cn;
      u16 hv = f2bf(hn);
      if (lhi == 0) {
        hbuf[t & 1][col0] = hv;
        outb[((size_t)(s * T_ + t)) * 256 + col0] =
            mode ? f2bf(gm0 * hn + bt0) : hv;
      }
    }
    {
      float iv = acc[1][0] + xi1, fv = acc[3][0] + xf1;
      float gv = acc[5][0] + xg1, ov = acc[7][0] + xo1;
      float cn = sigf(fv) * cs1 + sigf(iv) * tanhfast(gv);
      float hn = sigf(ov) * tanhfast(cn);
      cs1 = cn;
      u16 hv = f2bf(hn);
      if (lhi == 0) {
        hbuf[t & 1][col1] = hv;
        outb[((size_t)(s * T_ + t)) * 256 + col1] =
            mode ? f2bf(gm1 * hn + bt1) : hv;
      }
    }
    __syncthreads();   // h(t) visible to all waves; also covers W staging at t=0
  }
}

// ------------------------------ launcher -----------------------------------

extern "C" void kernel_launch(void* const* d_in, const int* in_sizes, int n_in,
                              void* d_out, int out_size, void* d_ws, size_t ws_size,
                              hipStream_t stream) {
  const float* z    = (const float*)d_in[0];
  const int*   seq  = (const int*)  d_in[1];
  const float* emb  = (const float*)d_in[2];
  const float* Wg   = (const float*)d_in[3];
  const float* bg   = (const float*)d_in[4];
  const float* Wb   = (const float*)d_in[5];
  const float* bb   = (const float*)d_in[6];
  const float* Wih0 = (const float*)d_in[7];
  const float* Whh0 = (const float*)d_in[8];
  const float* bih0 = (const float*)d_in[9];
  const float* bhh0 = (const float*)d_in[10];
  const float* Wih1 = (const float*)d_in[11];
  const float* Whh1 = (const float*)d_in[12];
  const float* bih1 = (const float*)d_in[13];
  const float* bhh1 = (const float*)d_in[14];
  const float* Wout = (const float*)d_in[15];
  const float* bout = (const float*)d_in[16];

  char* ws = (char*)d_ws;
  size_t off = 0;
  auto take = [&](size_t bytes) -> char* {
    char* p = ws + off;
    off = (off + bytes + 255) & ~(size_t)255;
    return p;
  };
  float* gamma  = (float*)take(B_ * H_ * 4);
  float* beta   = (float*)take(B_ * H_ * 4);
  float* b01    = (float*)take(G4 * 4);
  float* b11    = (float*)take(G4 * 4);
  u16*   Wih0b  = (u16*)  take((size_t)G4 * H_ * 2);
  u16*   Whh0b  = (u16*)  take((size_t)G4 * H_ * 2);
  u16*   Wih1b  = (u16*)  take((size_t)G4 * H_ * 2);
  u16*   Whh1b  = (u16*)  take((size_t)G4 * H_ * 2);
  u16*   Woutb  = (u16*)  take((size_t)V_ * H_ * 2);
  u16*   xb     = (u16*)  take((size_t)B_ * T_ * H_ * 2);
  float* X      = (float*)take((size_t)B_ * T_ * G4 * 4);
  u16*   h1b    = (u16*)  take((size_t)B_ * T_ * H_ * 2);
  u16*   filmb  = (u16*)  take((size_t)B_ * T_ * H_ * 2);
  (void)ws_size; (void)in_sizes; (void)n_in; (void)out_size;

  // prep
  k_convert<<<256, 256, 0, stream>>>(Wih0, Wih0b, G4 * H_);
  k_convert<<<256, 256, 0, stream>>>(Whh0, Whh0b, G4 * H_);
  k_convert<<<256, 256, 0, stream>>>(Wih1, Wih1b, G4 * H_);
  k_convert<<<256, 256, 0, stream>>>(Whh1, Whh1b, G4 * H_);
  k_convert<<<1024, 256, 0, stream>>>(Wout, Woutb, V_ * H_);
  k_addbias<<<4, 256, 0, stream>>>(bih0, bhh0, b01, G4);
  k_addbias<<<4, 256, 0, stream>>>(bih1, bhh1, b11, G4);
  k_film<<<32, 256, 0, stream>>>(z, Wg, bg, Wb, bb, gamma, beta);
  k_gather<<<1024, 256, 0, stream>>>(seq, emb, xb);

  // layer 0 input projection: X0 = x @ Wih0^T + (bih0+bhh0)
  k_gemm_bt<<<dim3(G4 / GBN, (B_ * T_) / GBM), 256, 0, stream>>>(
      xb, Wih0b, b01, X, B_ * T_, G4, H_);

  // layer 0 recurrence: one block per sample, no inter-block sync
  k_lstm_sample<<<B_, LTPB, 0, stream>>>(X, Whh0b, h1b, gamma, beta, 0);

  // layer 1 input projection: X1 = h1 @ Wih1^T + (bih1+bhh1)
  k_gemm_bt<<<dim3(G4 / GBN, (B_ * T_) / GBM), 256, 0, stream>>>(
      h1b, Wih1b, b11, X, B_ * T_, G4, H_);

  // layer 1 recurrence (FiLM fused into output)
  k_lstm_sample<<<B_, LTPB, 0, stream>>>(X, Whh1b, filmb, gamma, beta, 1);

  // logits = filmed @ Wout^T + b_out
  k_gemm_bt<<<dim3(V_ / GBN, (B_ * T_) / GBM), 256, 0, stream>>>(
      filmb, Woutb, bout, (float*)d_out, B_ * T_, V_, H_);
}

// Round 5
// 1166.071 us; speedup vs baseline: 2.7600x; 1.0320x over previous
//
#include <hip/hip_runtime.h>
#include <stdint.h>

// ---------------------------------------------------------------------------
// ConditionalDecoder: emb-gather -> LSTM x2 -> FiLM -> vocab GEMM
// B=16, T=256, V=32000, E=H=Z=256, 4H=1024
// Round 4: latency surgery on per-sample LSTM blocks:
//   - raw s_barrier (no vmcnt drain) per step; LDS-only h handoff
//   - permuted X layout -> 2x dwordx4 per step, prefetched 1 step ahead
//   - t=0 peeled; launch_bounds(512,2)
// ---------------------------------------------------------------------------

#define B_  16
#define T_  256
#define H_  256
#define V_  32000
#define G4  1024

#define LWAVES 8
#define LTPB   512
#define LRES   46        // B-frags resident in VGPR/AGPR per wave
#define LSTR   18        // B-frags streamed from LDS per wave

typedef unsigned short u16;
typedef __attribute__((ext_vector_type(8))) short  short8;
typedef __attribute__((ext_vector_type(4))) short  short4v;
typedef __attribute__((ext_vector_type(4))) float  f32x4;

static __device__ __forceinline__ float bf2f(u16 u) {
  uint32_t i = ((uint32_t)u) << 16;
  return __builtin_bit_cast(float, i);
}
static __device__ __forceinline__ u16 f2bf(float f) {
  uint32_t i = __builtin_bit_cast(uint32_t, f);
  uint32_t lsb = (i >> 16) & 1u;
  i += 0x7fffu + lsb;
  return (u16)(i >> 16);
}
static __device__ __forceinline__ float sigf(float x) {
  return 1.0f / (1.0f + __expf(-x));
}
static __device__ __forceinline__ float tanhfast(float x) {
  return 1.0f - 2.0f / (1.0f + __expf(2.0f * x));
}

// ------------------------------ prep kernels -------------------------------

__global__ void k_convert(const float* __restrict__ src, u16* __restrict__ dst, int n) {
  int i = blockIdx.x * blockDim.x + threadIdx.x;
  int stride = gridDim.x * blockDim.x;
  for (; i < n; i += stride) dst[i] = f2bf(src[i]);
}

__global__ void k_addbias(const float* __restrict__ a, const float* __restrict__ b,
                          float* __restrict__ dst, int n) {
  int i = blockIdx.x * blockDim.x + threadIdx.x;
  if (i < n) dst[i] = a[i] + b[i];
}

// gamma = z@Wg.T + bg ; beta = z@Wb.T + bb   (each (16,256))
__global__ void k_film(const float* __restrict__ z,
                       const float* __restrict__ Wg, const float* __restrict__ bg,
                       const float* __restrict__ Wb, const float* __restrict__ bb,
                       float* __restrict__ gamma, float* __restrict__ beta) {
  int tid = blockIdx.x * blockDim.x + threadIdx.x;   // 8192
  int which = tid >> 12;
  int o = tid & 4095;
  int b = o >> 8, h = o & 255;
  const float* W  = which ? Wb : Wg;
  const float* bi = which ? bb : bg;
  float acc = bi[h];
  const float* zr = z + b * 256;
  const float* wr = W + h * 256;
  #pragma unroll 8
  for (int k = 0; k < 256; k++) acc += zr[k] * wr[k];
  (which ? beta : gamma)[o] = acc;
}

// x[b][t][:] = (seq[b][t]==0 ? 0 : emb[seq[b][t]])  as bf16
__global__ void k_gather(const int* __restrict__ seq, const float* __restrict__ emb,
                         u16* __restrict__ xb) {
  int i = blockIdx.x * blockDim.x + threadIdx.x;     // B*T*(E/4) = 262144
  int n = B_ * T_ * (H_ / 4);
  if (i >= n) return;
  int e4 = i & 63;
  int bt = i >> 6;
  int t = bt & 255, b = bt >> 8;
  int row = seq[b * 257 + t];
  short4v p;
  if (row == 0) {
    p[0] = 0; p[1] = 0; p[2] = 0; p[3] = 0;
  } else {
    const f32x4 v = *(const f32x4*)(emb + (size_t)row * 256 + e4 * 4);
    p[0] = (short)f2bf(v[0]); p[1] = (short)f2bf(v[1]);
    p[2] = (short)f2bf(v[2]); p[3] = (short)f2bf(v[3]);
  }
  *(short4v*)(xb + (size_t)bt * 256 + e4 * 4) = p;
}

// ------------------------------ bf16 GEMM ----------------------------------
// C(M,N) fp32 = A(M,K)bf16 @ B(N,K)bf16^T + bias(N). M,N mult of 128, K mult of 32.
// permX: permute output column so the LSTM consumer's 8 gate values per
// (w,l15) are contiguous: pos = w*128 + l15*8 + g*2 + cb  (N must be 1024).

__global__ __launch_bounds__(256) void k_gemm_bt(
    const u16* __restrict__ A, const u16* __restrict__ Bm,
    const float* __restrict__ bias, float* __restrict__ C,
    int M, int N, int K, int permX) {
  __shared__ u16 sA[128 * 40];
  __shared__ u16 sB[128 * 40];
  const int tid  = threadIdx.x;
  const int lane = tid & 63;
  const int wv   = tid >> 6;
  const int wr   = wv >> 1, wc = wv & 1;
  const int m0 = blockIdx.y * 128, n0 = blockIdx.x * 128;
  const int rr = tid >> 2;
  const int cc = (tid & 3) * 8;

  f32x4 acc[4][4];
  #pragma unroll
  for (int m = 0; m < 4; m++)
    #pragma unroll
    for (int n = 0; n < 4; n++) acc[m][n] = (f32x4){0.f, 0.f, 0.f, 0.f};

  for (int ks = 0; ks < K; ks += 32) {
    short8 va0 = *(const short8*)(A  + (size_t)(m0 + rr)      * K + ks + cc);
    short8 va1 = *(const short8*)(A  + (size_t)(m0 + rr + 64) * K + ks + cc);
    short8 vb0 = *(const short8*)(Bm + (size_t)(n0 + rr)      * K + ks + cc);
    short8 vb1 = *(const short8*)(Bm + (size_t)(n0 + rr + 64) * K + ks + cc);
    __syncthreads();
    *(short8*)&sA[(rr)      * 40 + cc] = va0;
    *(short8*)&sA[(rr + 64) * 40 + cc] = va1;
    *(short8*)&sB[(rr)      * 40 + cc] = vb0;
    *(short8*)&sB[(rr + 64) * 40 + cc] = vb1;
    __syncthreads();
    const int kc = (lane >> 4) * 8;
    short8 af[4], bfr[4];
    #pragma unroll
    for (int m = 0; m < 4; m++)
      af[m] = *(const short8*)&sA[(wr * 64 + m * 16 + (lane & 15)) * 40 + kc];
    #pragma unroll
    for (int n = 0; n < 4; n++)
      bfr[n] = *(const short8*)&sB[(wc * 64 + n * 16 + (lane & 15)) * 40 + kc];
    #pragma unroll
    for (int m = 0; m < 4; m++)
      #pragma unroll
      for (int n = 0; n < 4; n++)
        acc[m][n] = __builtin_amdgcn_mfma_f32_16x16x32_bf16(af[m], bfr[n], acc[m][n], 0, 0, 0);
  }

  #pragma unroll
  for (int m = 0; m < 4; m++) {
    int row = m0 + wr * 64 + m * 16 + ((lane >> 4) << 2);
    #pragma unroll
    for (int n = 0; n < 4; n++) {
      int col = n0 + wc * 64 + n * 16 + (lane & 15);
      float bv = bias[col];
      int ocol = col;
      if (permX) {
        int g = col >> 8, r = col & 255;
        ocol = (r >> 5) * 128 + (col & 15) * 8 + g * 2 + ((r >> 4) & 1);
      }
      #pragma unroll
      for (int i = 0; i < 4; i++)
        C[(size_t)(row + i) * N + ocol] = acc[m][n][i] + bv;
    }
  }
}

// ------------------------- per-sample LSTM ---------------------------------
// Block = one sample. 8 waves; wave w owns h-cols [w*32,w*32+16) (cb=0) and
// [w*32+16,w*32+32) (cb=1) for all 4 gates = 8 MFMA N-tiles (tile = gate*2+cb).
// B-frag f = tile*8 + ks: f < LRES in regs, else LDS (staged pre-loop,
// wave-private). A = h(t-1) bf16 replicated over 16 MFMA rows.
// Raw s_barrier per step (LDS-only handoff: no vmcnt drain -> X prefetch
// survives across steps). X is permuted fp32: thread's 8 gate values at
// (s*T+t)*1024 + (w*16+l15)*8, order {i0,i1,f0,f1, g0,g1,o0,o1}.

#define LDSF(fi) (*(const short8*)&sWf[((w * LSTR + (fi)) * 64 + lane) * 8])

__global__ __launch_bounds__(LTPB, 2) void k_lstm_sample(
    const float* __restrict__ Xpre,    // (B*T, 1024) fp32 permuted
    const u16* __restrict__ Whh,       // (1024,256) bf16
    u16* __restrict__ outb,            // (B,T,H) bf16
    const float* __restrict__ gamma, const float* __restrict__ beta,
    int mode) {
  __shared__ u16 sWf[LWAVES * LSTR * 64 * 8];   // 144 KB streamed W frags
  __shared__ u16 hbuf[2][272];                  // h double buffer (bf16)

  const int s    = blockIdx.x;
  const int tid  = threadIdx.x;
  const int lane = tid & 63;
  const int w    = tid >> 6;
  const int l15  = lane & 15;
  const int lhi  = lane >> 4;

  // ---- stage W_hh fragments: LRES resident, LSTR -> LDS (wave-private) ----
  short8 wreg[LRES];
  #pragma unroll
  for (int tile = 0; tile < 8; ++tile) {
    const int row = (tile >> 1) * 256 + w * 32 + (tile & 1) * 16 + l15;
    const u16* wp = Whh + (size_t)row * 256 + lhi * 8;
    #pragma unroll
    for (int ks = 0; ks < 8; ++ks) {
      short8 v = *(const short8*)(wp + ks * 32);
      const int f = tile * 8 + ks;
      if (f < LRES) wreg[f] = v;
      else *(short8*)&sWf[((w * LSTR + (f - LRES)) * 64 + lane) * 8] = v;
    }
  }

  const int col0 = w * 32 + l15;
  const int col1 = col0 + 16;
  float cs0 = 0.f, cs1 = 0.f;
  float gm0 = 1.f, gm1 = 1.f, bt0 = 0.f, bt1 = 0.f;
  if (mode) {
    gm0 = gamma[s * 256 + col0]; bt0 = beta[s * 256 + col0];
    gm1 = gamma[s * 256 + col1]; bt1 = beta[s * 256 + col1];
  }

  const float* xptr = Xpre + (size_t)s * T_ * 1024 + (size_t)(w * 16 + l15) * 8;

  // ---- step t = 0 (no recurrent term) ----
  f32x4 xa = *(const f32x4*)(xptr);
  f32x4 xg = *(const f32x4*)(xptr + 4);
  {
    float cn0 = sigf(xa[2]) * cs0 + sigf(xa[0]) * tanhfast(xg[0]);
    float hn0 = sigf(xg[2]) * tanhfast(cn0);
    cs0 = cn0;
    float cn1 = sigf(xa[3]) * cs1 + sigf(xa[1]) * tanhfast(xg[1]);
    float hn1 = sigf(xg[3]) * tanhfast(cn1);
    cs1 = cn1;
    u16 h0 = f2bf(hn0), h1 = f2bf(hn1);
    if (lhi == 0) {
      hbuf[0][col0] = h0;
      hbuf[0][col1] = h1;
      outb[(size_t)(s * T_) * 256 + col0] = mode ? f2bf(gm0 * hn0 + bt0) : h0;
      outb[(size_t)(s * T_) * 256 + col1] = mode ? f2bf(gm1 * hn1 + bt1) : h1;
    }
  }
  asm volatile("s_waitcnt lgkmcnt(0)" ::: "memory");
  __builtin_amdgcn_sched_barrier(0);
  __builtin_amdgcn_s_barrier();
  __builtin_amdgcn_sched_barrier(0);

  // preload X for t=1
  xa = *(const f32x4*)(xptr + 1024);
  xg = *(const f32x4*)(xptr + 1024 + 4);

  for (int t = 1; t < T_; ++t) {
    // prefetch X for t+1 (clamped) -- consumed next iteration
    const float* xn = xptr + (size_t)((t + 1 < T_) ? t + 1 : t) * 1024;
    f32x4 na = *(const f32x4*)(xn);
    f32x4 ng = *(const f32x4*)(xn + 4);

    // ---- MFMA: h(t-1) @ Whh^T for this wave's 8 N-tiles ----
    const u16* hrd = hbuf[(t + 1) & 1];
    f32x4 acc[8];
    #pragma unroll
    for (int i = 0; i < 8; ++i) acc[i] = (f32x4){0.f, 0.f, 0.f, 0.f};
    #pragma unroll
    for (int ks = 0; ks < 8; ++ks) {
      short8 a = *(const short8*)&hrd[ks * 32 + lhi * 8];
      acc[0] = __builtin_amdgcn_mfma_f32_16x16x32_bf16(a, wreg[ks],      acc[0], 0, 0, 0);
      acc[1] = __builtin_amdgcn_mfma_f32_16x16x32_bf16(a, wreg[8 + ks],  acc[1], 0, 0, 0);
      acc[2] = __builtin_amdgcn_mfma_f32_16x16x32_bf16(a, wreg[16 + ks], acc[2], 0, 0, 0);
      acc[3] = __builtin_amdgcn_mfma_f32_16x16x32_bf16(a, wreg[24 + ks], acc[3], 0, 0, 0);
      acc[4] = __builtin_amdgcn_mfma_f32_16x16x32_bf16(a, wreg[32 + ks], acc[4], 0, 0, 0);
      if (40 + ks < LRES)
        acc[5] = __builtin_amdgcn_mfma_f32_16x16x32_bf16(a, wreg[40 + ks], acc[5], 0, 0, 0);
      else
        acc[5] = __builtin_amdgcn_mfma_f32_16x16x32_bf16(a, LDSF(ks - 6),  acc[5], 0, 0, 0);
      acc[6] = __builtin_amdgcn_mfma_f32_16x16x32_bf16(a, LDSF(2 + ks),  acc[6], 0, 0, 0);
      acc[7] = __builtin_amdgcn_mfma_f32_16x16x32_bf16(a, LDSF(10 + ks), acc[7], 0, 0, 0);
    }

    // ---- nonlinearity (rows replicated; any acc row works) ----
    {
      float iv = acc[0][0] + xa[0], fv = acc[2][0] + xa[2];
      float gv = acc[4][0] + xg[0], ov = acc[6][0] + xg[2];
      float cn = sigf(fv) * cs0 + sigf(iv) * tanhfast(gv);
      float hn = sigf(ov) * tanhfast(cn);
      cs0 = cn;
      u16 hv = f2bf(hn);
      if (lhi == 0) {
        hbuf[t & 1][col0] = hv;
        outb[((size_t)(s * T_ + t)) * 256 + col0] =
            mode ? f2bf(gm0 * hn + bt0) : hv;
      }
    }
    {
      float iv = acc[1][0] + xa[1], fv = acc[3][0] + xa[3];
      float gv = acc[5][0] + xg[1], ov = acc[7][0] + xg[3];
      float cn = sigf(fv) * cs1 + sigf(iv) * tanhfast(gv);
      float hn = sigf(ov) * tanhfast(cn);
      cs1 = cn;
      u16 hv = f2bf(hn);
      if (lhi == 0) {
        hbuf[t & 1][col1] = hv;
        outb[((size_t)(s * T_ + t)) * 256 + col1] =
            mode ? f2bf(gm1 * hn + bt1) : hv;
      }
    }

    // ---- raw barrier: LDS drained, VMEM left in flight ----
    asm volatile("s_waitcnt lgkmcnt(0)" ::: "memory");
    __builtin_amdgcn_sched_barrier(0);
    __builtin_amdgcn_s_barrier();
    __builtin_amdgcn_sched_barrier(0);

    xa = na;
    xg = ng;
  }
}

// ------------------------------ launcher -----------------------------------

extern "C" void kernel_launch(void* const* d_in, const int* in_sizes, int n_in,
                              void* d_out, int out_size, void* d_ws, size_t ws_size,
                              hipStream_t stream) {
  const float* z    = (const float*)d_in[0];
  const int*   seq  = (const int*)  d_in[1];
  const float* emb  = (const float*)d_in[2];
  const float* Wg   = (const float*)d_in[3];
  const float* bg   = (const float*)d_in[4];
  const float* Wb   = (const float*)d_in[5];
  const float* bb   = (const float*)d_in[6];
  const float* Wih0 = (const float*)d_in[7];
  const float* Whh0 = (const float*)d_in[8];
  const float* bih0 = (const float*)d_in[9];
  const float* bhh0 = (const float*)d_in[10];
  const float* Wih1 = (const float*)d_in[11];
  const float* Whh1 = (const float*)d_in[12];
  const float* bih1 = (const float*)d_in[13];
  const float* bhh1 = (const float*)d_in[14];
  const float* Wout = (const float*)d_in[15];
  const float* bout = (const float*)d_in[16];

  char* ws = (char*)d_ws;
  size_t off = 0;
  auto take = [&](size_t bytes) -> char* {
    char* p = ws + off;
    off = (off + bytes + 255) & ~(size_t)255;
    return p;
  };
  float* gamma  = (float*)take(B_ * H_ * 4);
  float* beta   = (float*)take(B_ * H_ * 4);
  float* b01    = (float*)take(G4 * 4);
  float* b11    = (float*)take(G4 * 4);
  u16*   Wih0b  = (u16*)  take((size_t)G4 * H_ * 2);
  u16*   Whh0b  = (u16*)  take((size_t)G4 * H_ * 2);
  u16*   Wih1b  = (u16*)  take((size_t)G4 * H_ * 2);
  u16*   Whh1b  = (u16*)  take((size_t)G4 * H_ * 2);
  u16*   Woutb  = (u16*)  take((size_t)V_ * H_ * 2);
  u16*   xb     = (u16*)  take((size_t)B_ * T_ * H_ * 2);
  float* X      = (float*)take((size_t)B_ * T_ * G4 * 4);
  u16*   h1b    = (u16*)  take((size_t)B_ * T_ * H_ * 2);
  u16*   filmb  = (u16*)  take((size_t)B_ * T_ * H_ * 2);
  (void)ws_size; (void)in_sizes; (void)n_in; (void)out_size;

  // prep
  k_convert<<<256, 256, 0, stream>>>(Wih0, Wih0b, G4 * H_);
  k_convert<<<256, 256, 0, stream>>>(Whh0, Whh0b, G4 * H_);
  k_convert<<<256, 256, 0, stream>>>(Wih1, Wih1b, G4 * H_);
  k_convert<<<256, 256, 0, stream>>>(Whh1, Whh1b, G4 * H_);
  k_convert<<<1024, 256, 0, stream>>>(Wout, Woutb, V_ * H_);
  k_addbias<<<4, 256, 0, stream>>>(bih0, bhh0, b01, G4);
  k_addbias<<<4, 256, 0, stream>>>(bih1, bhh1, b11, G4);
  k_film<<<32, 256, 0, stream>>>(z, Wg, bg, Wb, bb, gamma, beta);
  k_gather<<<1024, 256, 0, stream>>>(seq, emb, xb);

  // layer 0 input projection (permuted X layout)
  k_gemm_bt<<<dim3(G4 / 128, (B_ * T_) / 128), 256, 0, stream>>>(
      xb, Wih0b, b01, X, B_ * T_, G4, H_, 1);

  // layer 0 recurrence: one block per sample, no inter-block sync
  k_lstm_sample<<<B_, LTPB, 0, stream>>>(X, Whh0b, h1b, gamma, beta, 0);

  // layer 1 input projection (permuted X layout)
  k_gemm_bt<<<dim3(G4 / 128, (B_ * T_) / 128), 256, 0, stream>>>(
      h1b, Wih1b, b11, X, B_ * T_, G4, H_, 1);

  // layer 1 recurrence (FiLM fused into output)
  k_lstm_sample<<<B_, LTPB, 0, stream>>>(X, Whh1b, filmb, gamma, beta, 1);

  // logits = filmed @ Wout^T + b_out
  k_gemm_bt<<<dim3(V_ / 128, (B_ * T_) / 128), 256, 0, stream>>>(
      filmb, Woutb, bout, (float*)d_out, B_ * T_, V_, H_, 0);
}